// Round 5
// baseline (696.363 us; speedup 1.0000x reference)
//
#include <hip/hip_runtime.h>

// MeanAggregator: out[b,:] = features[nodes[b],:] + mean_k features[neigh_idx[b,k],:]
// features: [1M, 128] f32, nodes: [B] i32, neigh_idx: [B, 16] i32, out: [B, 128] f32
//
// R4 post-mortem: 692 us = 1.34 TB/s effective vs 6.46 TB/s demonstrated on this
// allocation -> latency-chain bound, not BW-bound. Fix: 4 rows per 32-lane group
// with 1-ahead index prefetch so the idx->gather serial head overlaps the previous
// row's 17 in-flight gathers.

typedef float f32x4 __attribute__((ext_vector_type(4)));
typedef int   i32x4 __attribute__((ext_vector_type(4)));

constexpr int FEAT_DIM = 128;
constexpr int FEAT_Q   = FEAT_DIM / 4;  // f32x4 chunks per row = 32
constexpr int K        = 16;            // num_sample (fixed by problem setup)
constexpr int ROWS     = 4;             // rows per 32-lane group

__global__ __launch_bounds__(256) void mean_agg_kernel(
    const float*  __restrict__ features,
    const int*    __restrict__ nodes,
    const int*    __restrict__ neigh_idx,
    float*        __restrict__ out,
    int batch)
{
    const int t  = blockIdx.x * blockDim.x + threadIdx.x;
    const int g  = t >> 5;           // 32-lane group id
    const int cq = t & 31;           // f32x4 column chunk, 0..31
    const int b0 = g * ROWS;
    if (b0 >= batch) return;

    const f32x4* f4  = reinterpret_cast<const f32x4*>(features);
    const i32x4* nip = reinterpret_cast<const i32x4*>(neigh_idx);  // 4 i32x4 per row

    // Prefetch row 0 indices (uniform within the 32-lane group -> HW broadcast).
    i32x4 j0 = nip[(size_t)b0 * 4 + 0];
    i32x4 j1 = nip[(size_t)b0 * 4 + 1];
    i32x4 j2 = nip[(size_t)b0 * 4 + 2];
    i32x4 j3 = nip[(size_t)b0 * 4 + 3];
    int   jn = nodes[b0];

#pragma unroll
    for (int r = 0; r < ROWS; ++r) {
        const int b = b0 + r;
        if (b >= batch) break;

        // Consume current row's indices; immediately issue next row's index
        // loads so they fly alongside this row's 17 gathers.
        const i32x4 i0 = j0, i1 = j1, i2 = j2, i3 = j3;
        const int   nd = jn;
        if (r + 1 < ROWS && b + 1 < batch) {
            j0 = nip[(size_t)(b + 1) * 4 + 0];
            j1 = nip[(size_t)(b + 1) * 4 + 1];
            j2 = nip[(size_t)(b + 1) * 4 + 2];
            j3 = nip[(size_t)(b + 1) * 4 + 3];
            jn = nodes[b + 1];
        }

        // 17 independent gathered 16B loads; each is a coalesced 512B row burst
        // across the 32-lane group.
        auto row = [&](int idx) -> f32x4 {
            return f4[(size_t)idx * FEAT_Q + cq];
        };

        const f32x4 nf  = row(nd);
        const f32x4 a0  = row(i0.x), a1  = row(i0.y), a2  = row(i0.z), a3  = row(i0.w);
        const f32x4 a4  = row(i1.x), a5  = row(i1.y), a6  = row(i1.z), a7  = row(i1.w);
        const f32x4 a8  = row(i2.x), a9  = row(i2.y), a10 = row(i2.z), a11 = row(i2.w);
        const f32x4 a12 = row(i3.x), a13 = row(i3.y), a14 = row(i3.z), a15 = row(i3.w);

        const f32x4 s =
            (((a0 + a1) + (a2 + a3)) + ((a4 + a5) + (a6 + a7))) +
            (((a8 + a9) + (a10 + a11)) + ((a12 + a13) + (a14 + a15)));

        constexpr float inv_k = 1.0f / (float)K;
        const f32x4 res = nf + s * inv_k;

        // Write-once output: nontemporal store keeps L2/L3 free for the gather.
        f32x4* op = reinterpret_cast<f32x4*>(out) + (size_t)b * FEAT_Q + cq;
        __builtin_nontemporal_store(res, op);
    }
}

extern "C" void kernel_launch(void* const* d_in, const int* in_sizes, int n_in,
                              void* d_out, int out_size, void* d_ws, size_t ws_size,
                              hipStream_t stream) {
    const float* features  = (const float*)d_in[0];
    const int*   nodes     = (const int*)d_in[1];
    const int*   neigh_idx = (const int*)d_in[2];
    // d_in[3] = num_sample scalar (always 16 per problem setup) — hard-coded as K.
    float* out = (float*)d_out;

    const int batch  = in_sizes[1];                         // 100,000
    const int groups = (batch + ROWS - 1) / ROWS;           // 25,000
    const int total_threads = groups * 32;
    const int block = 256;
    const int grid  = (total_threads + block - 1) / block;  // 3,125

    mean_agg_kernel<<<grid, block, 0, stream>>>(features, nodes, neigh_idx, out, batch);
}

// Round 7
// 693.877 us; speedup vs baseline: 1.0036x; 1.0036x over previous
//
#include <hip/hip_runtime.h>

// MeanAggregator: out[b,:] = features[nodes[b],:] + mean_k features[neigh_idx[b,k],:]
// features: [1M, 128] f32, nodes: [B] i32, neigh_idx: [B, 16] i32, out: [B, 128] f32
//
// R5 post-mortem: dur_us invariant under 4x structural change + kernel absent from
// top-5 dispatches (all ~317us harness fills) => real kernel < 315us, dur_us carries
// ~475us fixed harness restore overhead. Remaining lever: cut real kernel time.
//
// This version: ONE WAVE64 PER ROW, f32x2 per lane (64 lanes x 8B = 512B row burst).
// Row index b is wave-uniform -> readfirstlane forces it to SGPR, so:
//   - 16 neighbor indices + node id load as SCALAR s_load (off the vector pipe)
//   - each gather is global_load_dwordx2 v, v_laneoff, s[base]: one shared VGPR
//     lane offset, per-row base in SGPRs, ZERO per-load vector address math
//   - live VGPRs ~45 (17 x f32x2 + misc) -> 8 waves/SIMD (2x occupancy vs R4/R5)

typedef float f32x2 __attribute__((ext_vector_type(2)));

constexpr int FEAT_DIM = 128;
constexpr int FEAT_H   = FEAT_DIM / 2;  // f32x2 chunks per row = 64 (one per lane)
constexpr int K        = 16;            // num_sample (fixed by problem setup)

__global__ __launch_bounds__(256, 8) void mean_agg_kernel(
    const float*  __restrict__ features,
    const int*    __restrict__ nodes,
    const int*    __restrict__ neigh_idx,
    float*        __restrict__ out,
    int batch)
{
    const int t = blockIdx.x * blockDim.x + threadIdx.x;
    int b = t >> 6;                  // one wave64 per output row
    if (b >= batch) return;
    // b is uniform across the wave; readfirstlane proves it to the compiler so
    // index loads become s_load and gather bases live in SGPRs.
    b = __builtin_amdgcn_readfirstlane(b);
    const int lane = t & 63;

    // Uniform index loads -> scalar path (s_load_dwordx4/x16 + s_load_dword).
    const int* ni = neigh_idx + (size_t)b * K;
    int idx0  = ni[0],  idx1  = ni[1],  idx2  = ni[2],  idx3  = ni[3];
    int idx4  = ni[4],  idx5  = ni[5],  idx6  = ni[6],  idx7  = ni[7];
    int idx8  = ni[8],  idx9  = ni[9],  idx10 = ni[10], idx11 = ni[11];
    int idx12 = ni[12], idx13 = ni[13], idx14 = ni[14], idx15 = ni[15];
    const int nd = nodes[b];

    const f32x2* f2 = reinterpret_cast<const f32x2*>(features);

    // 17 independent gathers; each: SGPR base + shared lane offset, 512B/wave burst.
    auto row = [&](int idx) -> f32x2 {
        return f2[(size_t)idx * FEAT_H + lane];
    };

    const f32x2 nf  = row(nd);
    const f32x2 a0  = row(idx0),  a1  = row(idx1),  a2  = row(idx2),  a3  = row(idx3);
    const f32x2 a4  = row(idx4),  a5  = row(idx5),  a6  = row(idx6),  a7  = row(idx7);
    const f32x2 a8  = row(idx8),  a9  = row(idx9),  a10 = row(idx10), a11 = row(idx11);
    const f32x2 a12 = row(idx12), a13 = row(idx13), a14 = row(idx14), a15 = row(idx15);

    const f32x2 s =
        (((a0 + a1) + (a2 + a3)) + ((a4 + a5) + (a6 + a7))) +
        (((a8 + a9) + (a10 + a11)) + ((a12 + a13) + (a14 + a15)));

    constexpr float inv_k = 1.0f / (float)K;
    const f32x2 r = nf + s * inv_k;

    // Write-once output: nontemporal store keeps L2/L3 free for the gather.
    f32x2* op = reinterpret_cast<f32x2*>(out) + (size_t)b * FEAT_H + lane;
    __builtin_nontemporal_store(r, op);
}

extern "C" void kernel_launch(void* const* d_in, const int* in_sizes, int n_in,
                              void* d_out, int out_size, void* d_ws, size_t ws_size,
                              hipStream_t stream) {
    const float* features  = (const float*)d_in[0];
    const int*   nodes     = (const int*)d_in[1];
    const int*   neigh_idx = (const int*)d_in[2];
    // d_in[3] = num_sample scalar (always 16 per problem setup) — hard-coded as K.
    float* out = (float*)d_out;

    const int batch = in_sizes[1];              // 100,000
    const long long total_threads = (long long)batch * 64;  // one wave per row
    const int block = 256;
    const int grid  = (int)((total_threads + block - 1) / block);  // 25,000

    mean_agg_kernel<<<grid, block, 0, stream>>>(features, nodes, neigh_idx, out, batch);
}